// Round 9
// baseline (2753.601 us; speedup 1.0000x reference)
//
#include <hip/hip_runtime.h>
#include <hip/hip_bf16.h>

// ---------------------------------------------------------------------------
// Fused residual-MLP (N=65536, HID=512, NB=20) for gfx950.  Round 9.
//
// R8 post-mortem: 1 WG/CU is a HARD cap (96 unified regs/wave x 32 waves >
// 2048 pool) -> all gains must be intra-WG. Biggest VALU hotspot: in-GEMM
// stats unpack of bf16-packed hn (~96 VALU/thread/GEMM).
//
// R9: stats partials computed in the EPILOGUES from fp32 registers (t/h
// already live), pre-reduced 4-wide over the c-quad via shfl_xor(1,2)
// (DPP quad-perm, VALU-fused), stored fp32 in plane[64][66] float2
// (33.8 KB; writes 2-way, reads 2-way, b128-aligned stride 66).
// In-GEMM stats: 4xb128+96 VALU -> 2xb128+8 VALU. Phase A folded into
// epilogue2 (h already in regs there). Barriers stay 4/block:
//   bar1[hn+plane ready] gemm1(+mv1) bar2 epi1(hn=t, plane=t-stats)
//   bar3 gemm2(+mv2) bar4 epi2(h+=.., hn=h', plane=h'-stats) -> bar1
// Every producer->consumer pair barrier-audited (single hn, single plane,
// single mv all safe).  LDS: 66560 + 33792 + 512 = 100864 B (1 WG/CU).
// ---------------------------------------------------------------------------

typedef float  fvec4 __attribute__((ext_vector_type(4)));
typedef __bf16 bvec8 __attribute__((ext_vector_type(8)));

#define HN_STRIDE 520                 // ushorts per hn row (proven R1/R4-R8)
#define PL_STRIDE 66                  // float2 per plane row (16B-aligned, 2-way)
#define WCHUNK    16384               // ushorts per (b,slot,w) weight chunk
#define SMEM_BYTES (64*HN_STRIDE*2 + 64*PL_STRIDE*8 + 64*8)   // 100864
#define WPK_USHORTS ((size_t)20*2*16*WCHUNK)     // 10,485,760

__device__ __forceinline__ unsigned int f2bf(float v) {
    unsigned int u = __float_as_uint(v);
    return (u + 0x7fffu + ((u >> 16) & 1u)) >> 16;   // RNE to bf16
}
__device__ __forceinline__ unsigned int pkbf(float a, float b) {
    __hip_bfloat162 t = __float22bfloat162_rn(make_float2(a, b));
    unsigned int r;
    __builtin_memcpy(&r, &t, 4);                     // v_cvt_pk_bf16_f32
    return r;
}
__device__ __forceinline__ float silu_f(float v) {
    return v * (1.0f / (1.0f + __expf(-v)));
}

// ---- weight pre-pack: bf16(gamma_k * W[b][k][n]) in MFMA B-fragment order -
__global__ __launch_bounds__(256) void pack_weights(
        const float* __restrict__ w1, const float* __restrict__ w2,
        const float* __restrict__ g1, const float* __restrict__ g2,
        unsigned short* __restrict__ pk) {
    int tid = blockIdx.x * 256 + threadIdx.x;
    int l  = tid & 63;
    int f  = tid >> 6;
    int t  = f & 1;
    int kc = (f >> 1) & 15;
    int w  = (f >> 5) & 15;
    int g  = (f >> 9) & 1;
    int b  = f >> 10;
    const float* src = g ? w2 : w1;
    const float* gs  = (g ? g2 : g1) + b * 512;
    int k0 = kc * 32 + (l >> 4) * 8;
    int n  = w * 32 + (l & 15) * 2 + t;
    const float* s = src + ((size_t)b * 512 + k0) * 512 + n;
    unsigned int r[4];
#pragma unroll
    for (int j = 0; j < 4; ++j) {
        float ga = gs[k0 + 2 * j];
        float gb = gs[k0 + 2 * j + 1];
        unsigned int lo = f2bf(ga * s[(size_t)(2*j) * 512]);
        unsigned int hi = f2bf(gb * s[(size_t)(2*j + 1) * 512]);
        r[j] = lo | (hi << 16);
    }
    *(uint4*)(pk + (size_t)tid * 8) = make_uint4(r[0], r[1], r[2], r[3]);
}

// ---- u/vc precompute: u_n = sum_j g_j W_jn ; vc_n = sum_j beta_j W_jn + fcb_n
__global__ __launch_bounds__(512) void make_uv(
        const float* __restrict__ w1, const float* __restrict__ w2,
        const float* __restrict__ g1, const float* __restrict__ bl1,
        const float* __restrict__ cb1,
        const float* __restrict__ g2, const float* __restrict__ bl2,
        const float* __restrict__ cb2,
        float* __restrict__ uv) {
    int b = blockIdx.x >> 1, slot = blockIdx.x & 1, n = threadIdx.x;
    const float* W  = (slot ? w2 : w1) + (size_t)b * 512 * 512;
    const float* g  = (slot ? g2 : g1) + b * 512;
    const float* bl = (slot ? bl2 : bl1) + b * 512;
    const float* cb = (slot ? cb2 : cb1) + b * 512;
    float u = 0.f, v = 0.f;
    for (int j = 0; j < 512; ++j) {
        float wv = W[(size_t)j * 512 + n];
        u = fmaf(g[j], wv, u);
        v = fmaf(bl[j], wv, v);
    }
    uv[((b * 2 + slot) * 2 + 0) * 512 + n] = u;
    uv[((b * 2 + slot) * 2 + 1) * 512 + n] = v + cb[n];
}

// ---- GEMM with light mv-reduce interleaved (plane is fp32, pre-reduced) ---
__device__ __forceinline__ void gemm_red(
        fvec4 acc[4][2], const unsigned short* hn,
        const unsigned short* __restrict__ wp, uint4 pre0, uint4 pre1,
        const float2* plane2, float2* mv, int l, int c, int q, int tid) {
    const uint4* wp4 = (const uint4*)wp;
    const int r = tid >> 4, j = tid & 15;
    float s = 0.f, ss = 0.f;
#pragma unroll
    for (int kc = 0; kc < 16; ++kc) {
        bvec8 a[4], b0, b1;
#pragma unroll
        for (int rb = 0; rb < 4; ++rb)
            a[rb] = *(const bvec8*)(hn + (rb * 16 + c) * HN_STRIDE + kc * 32 + q * 8);
        if (kc == 0) {
            __builtin_memcpy(&b0, &pre0, 16);
            __builtin_memcpy(&b1, &pre1, 16);
        } else {
            uint4 r0 = wp4[(kc * 2 + 0) * 64 + l];
            uint4 r1 = wp4[(kc * 2 + 1) * 64 + l];
            __builtin_memcpy(&b0, &r0, 16);
            __builtin_memcpy(&b1, &r1, 16);
        }
        if (kc == 4) {
            float2 p0 = plane2[r * PL_STRIDE + j * 4 + 0];
            float2 p1 = plane2[r * PL_STRIDE + j * 4 + 1];
            s += p0.x + p1.x; ss += p0.y + p1.y;
        }
        if (kc == 5) {
            float2 p0 = plane2[r * PL_STRIDE + j * 4 + 2];
            float2 p1 = plane2[r * PL_STRIDE + j * 4 + 3];
            s += p0.x + p1.x; ss += p0.y + p1.y;
        }
#pragma unroll
        for (int rb = 0; rb < 4; ++rb) {
            acc[rb][0] = __builtin_amdgcn_mfma_f32_16x16x32_bf16(a[rb], b0, acc[rb][0], 0, 0, 0);
            acc[rb][1] = __builtin_amdgcn_mfma_f32_16x16x32_bf16(a[rb], b1, acc[rb][1], 0, 0, 0);
        }
    }
    s += __shfl_xor(s, 1); ss += __shfl_xor(ss, 1);
    s += __shfl_xor(s, 2); ss += __shfl_xor(ss, 2);
    s += __shfl_xor(s, 4); ss += __shfl_xor(ss, 4);
    s += __shfl_xor(s, 8); ss += __shfl_xor(ss, 8);
    if (j == 0) {
        float mean = s * (1.f / 512.f);
        float var  = ss * (1.f / 512.f) - mean * mean;
        mv[r] = make_float2(mean, rsqrtf(var + 1e-5f));
    }
}

// ---- standalone mv reduce from plane (final LN) ---------------------------
__device__ __forceinline__ void reduce_mv_plane(const float2* plane2,
                                                float2* mv, int tid) {
    int r = tid >> 4, j = tid & 15;
    float s = 0.f, ss = 0.f;
#pragma unroll
    for (int k = 0; k < 4; ++k) {
        float2 p = plane2[r * PL_STRIDE + j * 4 + k];
        s += p.x; ss += p.y;
    }
    s += __shfl_xor(s, 1); ss += __shfl_xor(ss, 1);
    s += __shfl_xor(s, 2); ss += __shfl_xor(ss, 2);
    s += __shfl_xor(s, 4); ss += __shfl_xor(ss, 4);
    s += __shfl_xor(s, 8); ss += __shfl_xor(ss, 8);
    if (j == 0) {
        float mean = s * (1.f / 512.f);
        float var  = ss * (1.f / 512.f) - mean * mean;
        mv[r] = make_float2(mean, rsqrtf(var + 1e-5f));
    }
}

__global__ __launch_bounds__(1024, 4) void mlp_fused(
        const float* __restrict__ x,
        const float* __restrict__ in_w,  const float* __restrict__ in_b,
        const float* __restrict__ out_ln_g, const float* __restrict__ out_ln_b,
        const float* __restrict__ out_w, const float* __restrict__ out_b,
        const unsigned short* __restrict__ wpk,
        const float* __restrict__ uv,
        float* __restrict__ out) {
    extern __shared__ char smem[];
    unsigned short* hn = (unsigned short*)smem;                  // 66560 B
    float* hnf = (float*)smem;                                   // alias (final)
    float2* plane2 = (float2*)(smem + 64 * HN_STRIDE * 2);       // 33792 B
    float2* mv = (float2*)(smem + 64 * HN_STRIDE * 2 + 64 * PL_STRIDE * 8);

    const int tid = threadIdx.x;
    const int w = tid >> 6;            // wave 0..15 -> cols [32w, 32w+32)
    const int l = tid & 63, c = l & 15, q = l >> 4;
    const int colbase = w * 32 + c * 2;
    const int row0 = blockIdx.x * 64;
    const int grp = w * 4 + (c >> 2);  // plane column group (4 pcols)
    const bool gw = (c & 3) == 0;      // group writer lane

    float h[4][4][2];   // [rb][i][t] : row rb*16+q*4+i, col colbase+t

    // emit hn(bf16) + fp32 pre-reduced stats partial for one (row, v0, v1)
    auto emit = [&](int row, float v0, float v1) {
        *(unsigned int*)(hn + row * HN_STRIDE + colbase) = pkbf(v0, v1);
        float s  = v0 + v1;
        float ss = __builtin_fmaf(v0, v0, v1 * v1);
        s += __shfl_xor(s, 1); ss += __shfl_xor(ss, 1);
        s += __shfl_xor(s, 2); ss += __shfl_xor(ss, 2);
        if (gw) plane2[row * PL_STRIDE + grp] = make_float2(s, ss);
    };

    // ---- in-proj + SiLU + initial hn/plane ----
    {
        float2 iw0 = *(const float2*)(in_w + colbase);
        float2 iw1 = *(const float2*)(in_w + 512 + colbase);
        float2 ib  = *(const float2*)(in_b + colbase);
#pragma unroll
        for (int rb = 0; rb < 4; ++rb)
#pragma unroll
            for (int i = 0; i < 4; ++i) {
                int row = rb * 16 + q * 4 + i;
                float2 xv = *(const float2*)(x + (size_t)(row0 + row) * 2);
                h[rb][i][0] = silu_f(xv.x * iw0.x + xv.y * iw1.x + ib.x);
                h[rb][i][1] = silu_f(xv.x * iw0.y + xv.y * iw1.y + ib.y);
                emit(row, h[rb][i][0], h[rb][i][1]);
            }
    }
    uint4 pre0 = ((const uint4*)(wpk + ((size_t)0 * 16 + w) * WCHUNK))[l];
    uint4 pre1 = ((const uint4*)(wpk + ((size_t)0 * 16 + w) * WCHUNK))[64 + l];

    for (int b = 0; b < 20; ++b) {
        const unsigned short* wp1 = wpk + ((size_t)(b * 2 + 0) * 16 + w) * WCHUNK;
        const unsigned short* wp2 = wpk + ((size_t)(b * 2 + 1) * 16 + w) * WCHUNK;
        int bn = (b < 19) ? (b + 1) * 2 : 38;   // next block's gemm1 (clamped)
        const unsigned short* wpn = wpk + ((size_t)bn * 16 + w) * WCHUNK;
        float2 u1  = *(const float2*)(uv + ((b * 2 + 0) * 2 + 0) * 512 + colbase);
        float2 vc1 = *(const float2*)(uv + ((b * 2 + 0) * 2 + 1) * 512 + colbase);
        float2 u2  = *(const float2*)(uv + ((b * 2 + 1) * 2 + 0) * 512 + colbase);
        float2 vc2 = *(const float2*)(uv + ((b * 2 + 1) * 2 + 1) * 512 + colbase);

        __syncthreads();                               // bar1: hn + plane ready

        fvec4 acc[4][2];
#pragma unroll
        for (int rb = 0; rb < 4; ++rb)
#pragma unroll
            for (int t = 0; t < 2; ++t) acc[rb][t] = (fvec4){0.f, 0.f, 0.f, 0.f};
        gemm_red(acc, hn, wp1, pre0, pre1, plane2, mv, l, c, q, tid);
        __syncthreads();                               // bar2: mv1 ready, hn reads done

        // epilogue1: t = silu(inv*acc - inv*m*u1 + vc1) -> hn + t-stats
        pre0 = ((const uint4*)wp2)[l];
        pre1 = ((const uint4*)wp2)[64 + l];
#pragma unroll
        for (int rb = 0; rb < 4; ++rb)
#pragma unroll
            for (int i = 0; i < 4; ++i) {
                int row = rb * 16 + q * 4 + i;
                float2 m = mv[row];
                float minv = -m.x * m.y;
                float t0 = silu_f(__builtin_fmaf(acc[rb][0][i], m.y,
                                  __builtin_fmaf(minv, u1.x, vc1.x)));
                float t1 = silu_f(__builtin_fmaf(acc[rb][1][i], m.y,
                                  __builtin_fmaf(minv, u1.y, vc1.y)));
                emit(row, t0, t1);
            }
        __syncthreads();                               // bar3: hn(t) + plane ready

#pragma unroll
        for (int rb = 0; rb < 4; ++rb)
#pragma unroll
            for (int t = 0; t < 2; ++t) acc[rb][t] = (fvec4){0.f, 0.f, 0.f, 0.f};
        gemm_red(acc, hn, wp2, pre0, pre1, plane2, mv, l, c, q, tid);
        __syncthreads();                               // bar4: mv2 ready, hn reads done

        // epilogue2: h += inv*acc - inv*m*u2 + vc2 ; emit next hn/plane
        pre0 = ((const uint4*)wpn)[l];
        pre1 = ((const uint4*)wpn)[64 + l];
#pragma unroll
        for (int rb = 0; rb < 4; ++rb)
#pragma unroll
            for (int i = 0; i < 4; ++i) {
                int row = rb * 16 + q * 4 + i;
                float2 m = mv[row];
                float minv = -m.x * m.y;
                h[rb][i][0] = __builtin_fmaf(acc[rb][0][i], m.y,
                    h[rb][i][0] + __builtin_fmaf(minv, u2.x, vc2.x));
                h[rb][i][1] = __builtin_fmaf(acc[rb][1][i], m.y,
                    h[rb][i][1] + __builtin_fmaf(minv, u2.y, vc2.y));
                emit(row, h[rb][i][0], h[rb][i][1]);
            }
    }

    // ---- final LN + SiLU + out-proj (plane already holds final h stats) ----
    __syncthreads();
    reduce_mv_plane(plane2, mv, tid);
    __syncthreads();
    {
        float2 og = *(const float2*)(out_ln_g + colbase);
        float2 ob = *(const float2*)(out_ln_b + colbase);
        float2 ow = *(const float2*)(out_w + colbase);
        const int pcol = w * 16 + c;
#pragma unroll
        for (int rb = 0; rb < 4; ++rb)
#pragma unroll
            for (int i = 0; i < 4; ++i) {
                int row = rb * 16 + q * 4 + i;
                float2 m = mv[row];
                float v0 = (h[rb][i][0] - m.x) * m.y * og.x + ob.x;
                float v1 = (h[rb][i][1] - m.x) * m.y * og.y + ob.y;
                hnf[pcol * 65 + row] = silu_f(v0) * ow.x + silu_f(v1) * ow.y;
            }
    }
    __syncthreads();
    {
        int r = tid >> 4, j = tid & 15;
        float s = 0.f;
#pragma unroll
        for (int u = 0; u < 16; ++u)
            s += hnf[(j + 16 * u) * 65 + r];
        s += __shfl_xor(s, 1);
        s += __shfl_xor(s, 2);
        s += __shfl_xor(s, 4);
        s += __shfl_xor(s, 8);
        if (j == 0) out[row0 + r] = s + out_b[0];
    }
}

extern "C" void kernel_launch(void* const* d_in, const int* in_sizes, int n_in,
                              void* d_out, int out_size, void* d_ws, size_t ws_size,
                              hipStream_t stream) {
    const float* x        = (const float*)d_in[0];
    const float* in_w     = (const float*)d_in[1];
    const float* in_b     = (const float*)d_in[2];
    const float* ln1_g    = (const float*)d_in[3];
    const float* ln1_b    = (const float*)d_in[4];
    const float* fc1_w    = (const float*)d_in[5];
    const float* fc1_b    = (const float*)d_in[6];
    const float* ln2_g    = (const float*)d_in[7];
    const float* ln2_b    = (const float*)d_in[8];
    const float* fc2_w    = (const float*)d_in[9];
    const float* fc2_b    = (const float*)d_in[10];
    const float* out_ln_g = (const float*)d_in[11];
    const float* out_ln_b = (const float*)d_in[12];
    const float* out_w    = (const float*)d_in[13];
    const float* out_b    = (const float*)d_in[14];
    float* out = (float*)d_out;
    unsigned short* wpk = (unsigned short*)d_ws;            // 20,971,520 B
    float* uv = (float*)((char*)d_ws + WPK_USHORTS * 2);    //    163,840 B

    (void)hipFuncSetAttribute((const void*)mlp_fused,
                              hipFuncAttributeMaxDynamicSharedMemorySize, SMEM_BYTES);

    pack_weights<<<5120, 256, 0, stream>>>(fc1_w, fc2_w, ln1_g, ln2_g, wpk);
    make_uv<<<40, 512, 0, stream>>>(fc1_w, fc2_w, ln1_g, ln1_b, fc1_b,
                                    ln2_g, ln2_b, fc2_b, uv);
    mlp_fused<<<1024, 1024, SMEM_BYTES, stream>>>(
        x, in_w, in_b, out_ln_g, out_ln_b, out_w, out_b, wpk, uv, out);
}

// Round 10
// 1832.493 us; speedup vs baseline: 1.5027x; 1.5027x over previous
//
#include <hip/hip_runtime.h>
#include <hip/hip_bf16.h>

// ---------------------------------------------------------------------------
// Fused residual-MLP (N=65536, HID=512, NB=20) for gfx950.  Round 10.
//
// R9 post-mortem: restructuring the epilogue/stats phases broke cross-WG L2
// phase coherence on the B-stream (FETCH 359MB -> 1.53GB, dur 1776->2754).
// R10 = byte-exact R8 structure (the 1776us kernel) + two local deltas:
//  (1) explicit distance-2 rotating-register pipeline for B-fragment loads
//      inside gemm_red (guarantees ~2 kc-iterations of L2 latency hiding);
//  (2) silu via v_rcp_f32 (1-ulp) instead of the full-precision divide
//      (~6 VALU saved x 32 silus/thread/block).
// Phase shapes, barriers, LDS layout, stats-in-GEMM: all R8-identical.
// ---------------------------------------------------------------------------

typedef float  fvec4 __attribute__((ext_vector_type(4)));
typedef __bf16 bvec8 __attribute__((ext_vector_type(8)));

#define HN_STRIDE 520                 // ushorts per hn row (proven R1/R4-R8)
#define WCHUNK    16384               // ushorts per (b,slot,w) weight chunk
#define SMEM_BYTES (64*HN_STRIDE*2 + 64*8)       // 66560 + 512 = 67072
#define WPK_USHORTS ((size_t)20*2*16*WCHUNK)     // 10,485,760

__device__ __forceinline__ unsigned int f2bf(float v) {
    unsigned int u = __float_as_uint(v);
    return (u + 0x7fffu + ((u >> 16) & 1u)) >> 16;   // RNE to bf16
}
__device__ __forceinline__ unsigned int pkbf(float a, float b) {
    __hip_bfloat162 t = __float22bfloat162_rn(make_float2(a, b));
    unsigned int r;
    __builtin_memcpy(&r, &t, 4);                     // v_cvt_pk_bf16_f32
    return r;
}
__device__ __forceinline__ float silu_f(float v) {
    return v * __builtin_amdgcn_rcpf(1.0f + __expf(-v));   // v_rcp_f32, 1-ulp
}

// ---- weight pre-pack: bf16(gamma_k * W[b][k][n]) in MFMA B-fragment order -
__global__ __launch_bounds__(256) void pack_weights(
        const float* __restrict__ w1, const float* __restrict__ w2,
        const float* __restrict__ g1, const float* __restrict__ g2,
        unsigned short* __restrict__ pk) {
    int tid = blockIdx.x * 256 + threadIdx.x;
    int l  = tid & 63;
    int f  = tid >> 6;
    int t  = f & 1;
    int kc = (f >> 1) & 15;
    int w  = (f >> 5) & 15;
    int g  = (f >> 9) & 1;
    int b  = f >> 10;
    const float* src = g ? w2 : w1;
    const float* gs  = (g ? g2 : g1) + b * 512;
    int k0 = kc * 32 + (l >> 4) * 8;
    int n  = w * 32 + (l & 15) * 2 + t;
    const float* s = src + ((size_t)b * 512 + k0) * 512 + n;
    unsigned int r[4];
#pragma unroll
    for (int j = 0; j < 4; ++j) {
        float ga = gs[k0 + 2 * j];
        float gb = gs[k0 + 2 * j + 1];
        unsigned int lo = f2bf(ga * s[(size_t)(2*j) * 512]);
        unsigned int hi = f2bf(gb * s[(size_t)(2*j + 1) * 512]);
        r[j] = lo | (hi << 16);
    }
    *(uint4*)(pk + (size_t)tid * 8) = make_uint4(r[0], r[1], r[2], r[3]);
}

// ---- u/vc precompute: u_n = sum_j g_j W_jn ; vc_n = sum_j beta_j W_jn + fcb_n
__global__ __launch_bounds__(512) void make_uv(
        const float* __restrict__ w1, const float* __restrict__ w2,
        const float* __restrict__ g1, const float* __restrict__ bl1,
        const float* __restrict__ cb1,
        const float* __restrict__ g2, const float* __restrict__ bl2,
        const float* __restrict__ cb2,
        float* __restrict__ uv) {
    int b = blockIdx.x >> 1, slot = blockIdx.x & 1, n = threadIdx.x;
    const float* W  = (slot ? w2 : w1) + (size_t)b * 512 * 512;
    const float* g  = (slot ? g2 : g1) + b * 512;
    const float* bl = (slot ? bl2 : bl1) + b * 512;
    const float* cb = (slot ? cb2 : cb1) + b * 512;
    float u = 0.f, v = 0.f;
    for (int j = 0; j < 512; ++j) {
        float wv = W[(size_t)j * 512 + n];
        u = fmaf(g[j], wv, u);
        v = fmaf(bl[j], wv, v);
    }
    uv[((b * 2 + slot) * 2 + 0) * 512 + n] = u;
    uv[((b * 2 + slot) * 2 + 1) * 512 + n] = v + cb[n];
}

__device__ __forceinline__ void acc_u32(unsigned int u, float& s, float& ss) {
    float lo = __uint_as_float(u << 16);
    float hi = __uint_as_float(u & 0xFFFF0000u);
    s += lo + hi;
    ss = __builtin_fmaf(lo, lo, ss);
    ss = __builtin_fmaf(hi, hi, ss);
}

// ---- GEMM with LN-stats reduce interleaved + distance-2 B pipeline --------
__device__ __forceinline__ void gemm_red(
        fvec4 acc[4][2], const unsigned short* hn,
        const unsigned short* __restrict__ wp, uint4 pre0, uint4 pre1,
        float2* mv, int l, int c, int q, int tid) {
    const uint4* wp4 = (const uint4*)wp;
    const int r = tid >> 4, j = tid & 15;
    float s = 0.f, ss = 0.f;
    uint4 c0 = pre0, c1 = pre1;          // kc+0 fragments (in regs)
    uint4 n0 = wp4[2 * 64 + l];          // kc+1 fragments (in flight)
    uint4 n1 = wp4[3 * 64 + l];
#pragma unroll
    for (int kc = 0; kc < 16; ++kc) {
        bvec8 a[4], b0, b1;
#pragma unroll
        for (int rb = 0; rb < 4; ++rb)
            a[rb] = *(const bvec8*)(hn + (rb * 16 + c) * HN_STRIDE + kc * 32 + q * 8);
        __builtin_memcpy(&b0, &c0, 16);
        __builtin_memcpy(&b1, &c1, 16);
        c0 = n0; c1 = n1;                // rotate pipeline
        if (kc < 14) {                   // issue kc+2 loads now
            n0 = wp4[((kc + 2) * 2 + 0) * 64 + l];
            n1 = wp4[((kc + 2) * 2 + 1) * 64 + l];
        }
        if (kc >= 4 && kc < 8) {   // 4 stats chunks hidden under the MFMA stream
            uint4 pv = *(const uint4*)(hn + r * HN_STRIDE + (j + 16 * (kc - 4)) * 8);
            acc_u32(pv.x, s, ss); acc_u32(pv.y, s, ss);
            acc_u32(pv.z, s, ss); acc_u32(pv.w, s, ss);
        }
#pragma unroll
        for (int rb = 0; rb < 4; ++rb) {
            acc[rb][0] = __builtin_amdgcn_mfma_f32_16x16x32_bf16(a[rb], b0, acc[rb][0], 0, 0, 0);
            acc[rb][1] = __builtin_amdgcn_mfma_f32_16x16x32_bf16(a[rb], b1, acc[rb][1], 0, 0, 0);
        }
    }
    s += __shfl_xor(s, 1); ss += __shfl_xor(ss, 1);
    s += __shfl_xor(s, 2); ss += __shfl_xor(ss, 2);
    s += __shfl_xor(s, 4); ss += __shfl_xor(ss, 4);
    s += __shfl_xor(s, 8); ss += __shfl_xor(ss, 8);
    if (j == 0) {
        float mean = s * (1.f / 512.f);
        float var  = ss * (1.f / 512.f) - mean * mean;
        mv[r] = make_float2(mean, rsqrtf(var + 1e-5f));
    }
}

// ---- standalone stats from hn (final LN) ----------------------------------
__device__ __forceinline__ void reduce_mv_hn(const unsigned short* hn,
                                             float2* mv, int tid) {
    int r = tid >> 4, j = tid & 15;
    float s = 0.f, ss = 0.f;
#pragma unroll
    for (int u = 0; u < 4; ++u) {
        uint4 pv = *(const uint4*)(hn + r * HN_STRIDE + (j + 16 * u) * 8);
        acc_u32(pv.x, s, ss); acc_u32(pv.y, s, ss);
        acc_u32(pv.z, s, ss); acc_u32(pv.w, s, ss);
    }
    s += __shfl_xor(s, 1); ss += __shfl_xor(ss, 1);
    s += __shfl_xor(s, 2); ss += __shfl_xor(ss, 2);
    s += __shfl_xor(s, 4); ss += __shfl_xor(ss, 4);
    s += __shfl_xor(s, 8); ss += __shfl_xor(ss, 8);
    if (j == 0) {
        float mean = s * (1.f / 512.f);
        float var  = ss * (1.f / 512.f) - mean * mean;
        mv[r] = make_float2(mean, rsqrtf(var + 1e-5f));
    }
}

__global__ __launch_bounds__(1024, 4) void mlp_fused(
        const float* __restrict__ x,
        const float* __restrict__ in_w,  const float* __restrict__ in_b,
        const float* __restrict__ out_ln_g, const float* __restrict__ out_ln_b,
        const float* __restrict__ out_w, const float* __restrict__ out_b,
        const unsigned short* __restrict__ wpk,
        const float* __restrict__ uv,
        float* __restrict__ out) {
    extern __shared__ char smem[];
    unsigned short* hn = (unsigned short*)smem;                  // 66560 B
    float* hnf = (float*)smem;                                   // alias (final)
    float2* mv = (float2*)(smem + 64 * HN_STRIDE * 2);           //   512 B

    const int tid = threadIdx.x;
    const int w = tid >> 6;            // wave 0..15 -> cols [32w, 32w+32)
    const int l = tid & 63, c = l & 15, q = l >> 4;
    const int colbase = w * 32 + c * 2;
    const int row0 = blockIdx.x * 64;

    float h[4][4][2];   // [rb][i][t] : row rb*16+q*4+i, col colbase+t

    // ---- in-proj + SiLU ----
    {
        float2 iw0 = *(const float2*)(in_w + colbase);
        float2 iw1 = *(const float2*)(in_w + 512 + colbase);
        float2 ib  = *(const float2*)(in_b + colbase);
#pragma unroll
        for (int rb = 0; rb < 4; ++rb)
#pragma unroll
            for (int i = 0; i < 4; ++i) {
                int row = rb * 16 + q * 4 + i;
                float2 xv = *(const float2*)(x + (size_t)(row0 + row) * 2);
                h[rb][i][0] = silu_f(xv.x * iw0.x + xv.y * iw1.x + ib.x);
                h[rb][i][1] = silu_f(xv.x * iw0.y + xv.y * iw1.y + ib.y);
            }
    }

    for (int b = 0; b < 20; ++b) {
        const unsigned short* wp1 = wpk + ((size_t)(b * 2 + 0) * 16 + w) * WCHUNK;
        const unsigned short* wp2 = wpk + ((size_t)(b * 2 + 1) * 16 + w) * WCHUNK;
        float2 u1  = *(const float2*)(uv + ((b * 2 + 0) * 2 + 0) * 512 + colbase);
        float2 vc1 = *(const float2*)(uv + ((b * 2 + 0) * 2 + 1) * 512 + colbase);
        float2 u2  = *(const float2*)(uv + ((b * 2 + 1) * 2 + 0) * 512 + colbase);
        float2 vc2 = *(const float2*)(uv + ((b * 2 + 1) * 2 + 1) * 512 + colbase);

        // phase A: hn = bf16(h) (packed cast) + prefetch gemm1 kc=0 B-frags
        uint4 pre0 = ((const uint4*)wp1)[l];
        uint4 pre1 = ((const uint4*)wp1)[64 + l];
#pragma unroll
        for (int rb = 0; rb < 4; ++rb)
#pragma unroll
            for (int i = 0; i < 4; ++i) {
                int row = rb * 16 + q * 4 + i;
                *(unsigned int*)(hn + row * HN_STRIDE + colbase) =
                    pkbf(h[rb][i][0], h[rb][i][1]);
            }
        __syncthreads();                               // bar1

        fvec4 acc[4][2];
#pragma unroll
        for (int rb = 0; rb < 4; ++rb)
#pragma unroll
            for (int t = 0; t < 2; ++t) acc[rb][t] = (fvec4){0.f, 0.f, 0.f, 0.f};
        gemm_red(acc, hn, wp1, pre0, pre1, mv, l, c, q, tid);
        __syncthreads();                               // bar2 (mv1 + hn reads done)

        // epilogue1: t = silu(inv*acc - inv*m*u1 + vc1) -> hn ; prefetch gemm2
        pre0 = ((const uint4*)wp2)[l];
        pre1 = ((const uint4*)wp2)[64 + l];
#pragma unroll
        for (int rb = 0; rb < 4; ++rb)
#pragma unroll
            for (int i = 0; i < 4; ++i) {
                int row = rb * 16 + q * 4 + i;
                float2 m = mv[row];
                float minv = -m.x * m.y;
                float t0 = silu_f(__builtin_fmaf(acc[rb][0][i], m.y,
                                  __builtin_fmaf(minv, u1.x, vc1.x)));
                float t1 = silu_f(__builtin_fmaf(acc[rb][1][i], m.y,
                                  __builtin_fmaf(minv, u1.y, vc1.y)));
                *(unsigned int*)(hn + row * HN_STRIDE + colbase) = pkbf(t0, t1);
            }
        __syncthreads();                               // bar3

#pragma unroll
        for (int rb = 0; rb < 4; ++rb)
#pragma unroll
            for (int t = 0; t < 2; ++t) acc[rb][t] = (fvec4){0.f, 0.f, 0.f, 0.f};
        gemm_red(acc, hn, wp2, pre0, pre1, mv, l, c, q, tid);
        __syncthreads();                               // bar4 (mv2 + hn reads done)

        // epilogue2: h += inv*acc - inv*m*u2 + vc2   (residual in fp32)
#pragma unroll
        for (int rb = 0; rb < 4; ++rb)
#pragma unroll
            for (int i = 0; i < 4; ++i) {
                int row = rb * 16 + q * 4 + i;
                float2 m = mv[row];
                float minv = -m.x * m.y;
                h[rb][i][0] = __builtin_fmaf(acc[rb][0][i], m.y,
                    h[rb][i][0] + __builtin_fmaf(minv, u2.x, vc2.x));
                h[rb][i][1] = __builtin_fmaf(acc[rb][1][i], m.y,
                    h[rb][i][1] + __builtin_fmaf(minv, u2.y, vc2.y));
            }
    }

    // ---- final LN + SiLU + out-proj ----
#pragma unroll
    for (int rb = 0; rb < 4; ++rb)
#pragma unroll
        for (int i = 0; i < 4; ++i) {
            int row = rb * 16 + q * 4 + i;
            *(unsigned int*)(hn + row * HN_STRIDE + colbase) =
                pkbf(h[rb][i][0], h[rb][i][1]);
        }
    __syncthreads();
    reduce_mv_hn(hn, mv, tid);
    __syncthreads();
    {
        float2 og = *(const float2*)(out_ln_g + colbase);
        float2 ob = *(const float2*)(out_ln_b + colbase);
        float2 ow = *(const float2*)(out_w + colbase);
        const int pcol = w * 16 + c;
#pragma unroll
        for (int rb = 0; rb < 4; ++rb)
#pragma unroll
            for (int i = 0; i < 4; ++i) {
                int row = rb * 16 + q * 4 + i;
                float2 m = mv[row];
                float v0 = (h[rb][i][0] - m.x) * m.y * og.x + ob.x;
                float v1 = (h[rb][i][1] - m.x) * m.y * og.y + ob.y;
                hnf[pcol * 65 + row] = silu_f(v0) * ow.x + silu_f(v1) * ow.y;
            }
    }
    __syncthreads();
    {
        int r = tid >> 4, j = tid & 15;
        float s = 0.f;
#pragma unroll
        for (int u = 0; u < 16; ++u)
            s += hnf[(j + 16 * u) * 65 + r];
        s += __shfl_xor(s, 1);
        s += __shfl_xor(s, 2);
        s += __shfl_xor(s, 4);
        s += __shfl_xor(s, 8);
        if (j == 0) out[row0 + r] = s + out_b[0];
    }
}

extern "C" void kernel_launch(void* const* d_in, const int* in_sizes, int n_in,
                              void* d_out, int out_size, void* d_ws, size_t ws_size,
                              hipStream_t stream) {
    const float* x        = (const float*)d_in[0];
    const float* in_w     = (const float*)d_in[1];
    const float* in_b     = (const float*)d_in[2];
    const float* ln1_g    = (const float*)d_in[3];
    const float* ln1_b    = (const float*)d_in[4];
    const float* fc1_w    = (const float*)d_in[5];
    const float* fc1_b    = (const float*)d_in[6];
    const float* ln2_g    = (const float*)d_in[7];
    const float* ln2_b    = (const float*)d_in[8];
    const float* fc2_w    = (const float*)d_in[9];
    const float* fc2_b    = (const float*)d_in[10];
    const float* out_ln_g = (const float*)d_in[11];
    const float* out_ln_b = (const float*)d_in[12];
    const float* out_w    = (const float*)d_in[13];
    const float* out_b    = (const float*)d_in[14];
    float* out = (float*)d_out;
    unsigned short* wpk = (unsigned short*)d_ws;            // 20,971,520 B
    float* uv = (float*)((char*)d_ws + WPK_USHORTS * 2);    //    163,840 B

    (void)hipFuncSetAttribute((const void*)mlp_fused,
                              hipFuncAttributeMaxDynamicSharedMemorySize, SMEM_BYTES);

    pack_weights<<<5120, 256, 0, stream>>>(fc1_w, fc2_w, ln1_g, ln2_g, wpk);
    make_uv<<<40, 512, 0, stream>>>(fc1_w, fc2_w, ln1_g, ln1_b, fc1_b,
                                    ln2_g, ln2_b, fc2_b, uv);
    mlp_fused<<<1024, 1024, SMEM_BYTES, stream>>>(
        x, in_w, in_b, out_ln_g, out_ln_b, out_w, out_b, wpk, uv, out);
}